// Round 2
// baseline (3485.743 us; speedup 1.0000x reference)
//
#include <hip/hip_runtime.h>
#include <cstdint>
#include <cstddef>

#define NN 100000      // nodes
#define NE 1600000     // edges
#define FD 128         // feature dim
#define HD2 256        // hidden*2
#define NLAYERS 4
#define NGR 512        // graphs
#define NCLS 10
#define BNEPS 1e-5f

// ---------------- index dtype normalization ----------------
// If edge_index/batch arrived as int64, every odd 32-bit word (high half) is 0
// (values are in [0,1e5)). With int32 data, odd words are random src indices.
__global__ void k_detect(const int* ei, int* flag) {
  __shared__ int nz;
  if (threadIdx.x == 0) nz = 0;
  __syncthreads();
  if (ei[2 * threadIdx.x + 1] != 0) atomicAdd(&nz, 1);
  __syncthreads();
  if (threadIdx.x == 0) flag[0] = (nz == 0) ? 1 : 0;  // 1 => int64
}

__global__ void k_repack(const int* ei, const int* batch, const int* flag,
                         int* src32, int* dst32, int* batch32) {
  int i = blockIdx.x * 256 + threadIdx.x;
  const bool wide = (flag[0] != 0);
  if (i < NE) {
    src32[i] = wide ? ei[2 * i] : ei[i];
    dst32[i] = wide ? ei[2 * (NE + i)] : ei[NE + i];
  }
  if (i < NN) batch32[i] = wide ? batch[2 * i] : batch[i];
}

// ---------------- setup ----------------
__global__ void k_init(int* degi, float* gcnt, float* gsum) {
  int i = blockIdx.x * 256 + threadIdx.x;
  if (i < NN) degi[i] = 0;
  if (i < NGR) gcnt[i] = 0.f;
  if (i < NGR * (FD * NLAYERS)) gsum[i] = 0.f;
}

__global__ void k_deg_gcnt(const int* dst, int* degi, const int* batch, float* gcnt) {
  int i = blockIdx.x * 256 + threadIdx.x;
  if (i < NE) atomicAdd(&degi[dst[i]], 1);
  if (i < NN) atomicAdd(&gcnt[batch[i]], 1.f);
}

// exclusive prefix sum of degrees -> rowptr (3-phase block scan)
__global__ void k_scan1(const int* degi, int* rowptr, int* bsum) {
  __shared__ int s[256];
  int t = threadIdx.x;
  int i = blockIdx.x * 256 + t;
  int v = (i < NN) ? degi[i] : 0;
  s[t] = v;
  __syncthreads();
  for (int off = 1; off < 256; off <<= 1) {
    int x = (t >= off) ? s[t - off] : 0;
    __syncthreads();
    s[t] += x;
    __syncthreads();
  }
  if (i < NN) rowptr[i] = s[t] - v;          // local exclusive
  if (t == 255) bsum[blockIdx.x] = s[255];   // block total
}

__global__ void k_scan2(int* bsum, int nb) {
  __shared__ int s[512];
  int t = threadIdx.x;
  int v = (t < nb) ? bsum[t] : 0;
  s[t] = v;
  __syncthreads();
  for (int off = 1; off < 512; off <<= 1) {
    int x = (t >= off) ? s[t - off] : 0;
    __syncthreads();
    s[t] += x;
    __syncthreads();
  }
  if (t < nb) bsum[t] = s[t] - v;            // exclusive block offsets
}

__global__ void k_scan3_cursor(int* rowptr, const int* bsum, int* cursor,
                               const int* degi, float* inv_deg) {
  int i = blockIdx.x * 256 + threadIdx.x;
  if (i < NN) {
    int r = rowptr[i] + bsum[blockIdx.x];
    rowptr[i] = r;
    cursor[i] = r;
    inv_deg[i] = 1.f / fmaxf((float)degi[i], 1.f);
  }
  if (i == 0) rowptr[NN] = NE;
}

__global__ void k_scatter(const int* src, const int* dst, int* cursor, int* csr) {
  int e = blockIdx.x * 256 + threadIdx.x;
  if (e < NE) {
    int p = atomicAdd(&cursor[dst[e]], 1);
    csr[p] = src[e];
  }
}

// ---------------- per-layer kernels ----------------
// t[v] = h[v] + inv_deg[v] * sum_{u in N(v)} h[u]   (2 nodes / 256-thread block)
__global__ void k_agg(const float* __restrict__ h, const int* __restrict__ rowptr,
                      const int* __restrict__ csr, const float* __restrict__ inv_deg,
                      float* __restrict__ tout, float* bnsum) {
  // zero ALL 2*HD2 BN accumulators (256 threads -> 2 entries each)
  if (blockIdx.x == 0) {
    bnsum[threadIdx.x] = 0.f;
    bnsum[HD2 + threadIdx.x] = 0.f;
  }
  int node = blockIdx.x * 2 + (threadIdx.x >> 7);
  int f = threadIdx.x & (FD - 1);
  if (node >= NN) return;
  int beg = rowptr[node], end = rowptr[node + 1];
  float acc = 0.f;
  for (int j = beg; j < end; ++j) {
    int s = csr[j];
    acc += h[(size_t)s * FD + f];
  }
  tout[(size_t)node * FD + f] = h[(size_t)node * FD + f] + acc * inv_deg[node];
}

// Z = A @ W1 + b1; accumulate per-column sum / sumsq for BN.
// A: [NN,128], W: [128,256], 64x64 tile, BK=16, 256 threads, 4x4 per thread.
__launch_bounds__(256)
__global__ void k_gemm1(const float* __restrict__ A, const float* __restrict__ W,
                        const float* __restrict__ bias, float* __restrict__ Z,
                        float* __restrict__ bnsum) {
  __shared__ float As[16][68];   // [k][m], padded (272B row = 17*16B, float4-aligned)
  __shared__ float Bs[16][64];   // [k][n]
  __shared__ float colsum[64], colsum2[64];
  const int tid = threadIdx.x;
  const int tx = tid & 15, ty = tid >> 4;
  const int row0 = blockIdx.x * 64, col0 = blockIdx.y * 64;
  const int lr = tid >> 2, lk = (tid & 3) * 4;       // A-tile load coords
  const int wk = tid >> 4, wn = (tid & 15) * 4;      // B-tile load coords
  int arow = row0 + lr; if (arow >= NN) arow = NN - 1;
  float acc[4][4] = {};
  for (int k0 = 0; k0 < FD; k0 += 16) {
    float4 a4 = *(const float4*)&A[(size_t)arow * FD + k0 + lk];
    float4 b4 = *(const float4*)&W[(size_t)(k0 + wk) * HD2 + col0 + wn];
    As[lk + 0][lr] = a4.x; As[lk + 1][lr] = a4.y;
    As[lk + 2][lr] = a4.z; As[lk + 3][lr] = a4.w;
    *(float4*)&Bs[wk][wn] = b4;
    __syncthreads();
#pragma unroll
    for (int kk = 0; kk < 16; ++kk) {
      float4 av = *(const float4*)&As[kk][ty * 4];
      float4 bv = *(const float4*)&Bs[kk][tx * 4];
      const float aa[4] = {av.x, av.y, av.z, av.w};
      const float bb[4] = {bv.x, bv.y, bv.z, bv.w};
#pragma unroll
      for (int i = 0; i < 4; ++i)
#pragma unroll
        for (int j = 0; j < 4; ++j) acc[i][j] += aa[i] * bb[j];
    }
    __syncthreads();
  }
  float4 bv4 = *(const float4*)&bias[col0 + tx * 4];
  const float bb[4] = {bv4.x, bv4.y, bv4.z, bv4.w};
  float cs0[4] = {0, 0, 0, 0}, cs1[4] = {0, 0, 0, 0};
#pragma unroll
  for (int i = 0; i < 4; ++i) {
    int row = row0 + ty * 4 + i;
    if (row < NN) {
      float z[4];
#pragma unroll
      for (int j = 0; j < 4; ++j) {
        z[j] = acc[i][j] + bb[j];
        cs0[j] += z[j];
        cs1[j] += z[j] * z[j];
      }
      *(float4*)&Z[(size_t)row * HD2 + col0 + tx * 4] = make_float4(z[0], z[1], z[2], z[3]);
    }
  }
  if (tid < 64) { colsum[tid] = 0.f; colsum2[tid] = 0.f; }
  __syncthreads();
#pragma unroll
  for (int j = 0; j < 4; ++j) {
    atomicAdd(&colsum[tx * 4 + j], cs0[j]);
    atomicAdd(&colsum2[tx * 4 + j], cs1[j]);
  }
  __syncthreads();
  if (tid < 64) {
    atomicAdd(&bnsum[col0 + tid], colsum[tid]);
    atomicAdd(&bnsum[HD2 + col0 + tid], colsum2[tid]);
  }
}

// fold BN into affine: y = z*a1[c] + a2[c]
__global__ void k_bnfin(const float* bnsum, const float* gamma, const float* beta, float* a12) {
  int c = threadIdx.x;
  if (c < HD2) {
    float mu = bnsum[c] * (1.f / (float)NN);
    float var = fmaxf(bnsum[HD2 + c] * (1.f / (float)NN) - mu * mu, 0.f);
    float rs = rsqrtf(var + BNEPS);
    float g = gamma[c] * rs;
    a12[c] = g;
    a12[HD2 + c] = beta[c] - mu * g;
  }
}

// H = relu( relu(BN(Z)) @ W2 + b2 ); pool into gsum. Z: [NN,256], W: [256,128].
__launch_bounds__(256)
__global__ void k_gemm2(const float* __restrict__ Z, const float* __restrict__ W,
                        const float* __restrict__ bias, const float* __restrict__ a12,
                        const int* __restrict__ batch, float* __restrict__ Hout,
                        float* __restrict__ gsum, int layer) {
  __shared__ float As[16][68];
  __shared__ float Bs[16][64];
  __shared__ float sa1[HD2], sa2[HD2];
  const int tid = threadIdx.x;
  sa1[tid] = a12[tid];
  sa2[tid] = a12[HD2 + tid];
  const int tx = tid & 15, ty = tid >> 4;
  const int row0 = blockIdx.x * 64, col0 = blockIdx.y * 64;
  const int lr = tid >> 2, lk = (tid & 3) * 4;
  const int wk = tid >> 4, wn = (tid & 15) * 4;
  int arow = row0 + lr; if (arow >= NN) arow = NN - 1;
  float acc[4][4] = {};
  __syncthreads();  // sa1/sa2 ready
  for (int k0 = 0; k0 < HD2; k0 += 16) {
    float4 a4 = *(const float4*)&Z[(size_t)arow * HD2 + k0 + lk];
    float4 b4 = *(const float4*)&W[(size_t)(k0 + wk) * FD + col0 + wn];
    int kb = k0 + lk;
    As[lk + 0][lr] = fmaxf(a4.x * sa1[kb + 0] + sa2[kb + 0], 0.f);
    As[lk + 1][lr] = fmaxf(a4.y * sa1[kb + 1] + sa2[kb + 1], 0.f);
    As[lk + 2][lr] = fmaxf(a4.z * sa1[kb + 2] + sa2[kb + 2], 0.f);
    As[lk + 3][lr] = fmaxf(a4.w * sa1[kb + 3] + sa2[kb + 3], 0.f);
    *(float4*)&Bs[wk][wn] = b4;
    __syncthreads();
#pragma unroll
    for (int kk = 0; kk < 16; ++kk) {
      float4 av = *(const float4*)&As[kk][ty * 4];
      float4 bv = *(const float4*)&Bs[kk][tx * 4];
      const float aa[4] = {av.x, av.y, av.z, av.w};
      const float bb[4] = {bv.x, bv.y, bv.z, bv.w};
#pragma unroll
      for (int i = 0; i < 4; ++i)
#pragma unroll
        for (int j = 0; j < 4; ++j) acc[i][j] += aa[i] * bb[j];
    }
    __syncthreads();
  }
  float4 bv4 = *(const float4*)&bias[col0 + tx * 4];
  const float bb[4] = {bv4.x, bv4.y, bv4.z, bv4.w};
#pragma unroll
  for (int i = 0; i < 4; ++i) {
    int row = row0 + ty * 4 + i;
    if (row < NN) {
      float h[4];
#pragma unroll
      for (int j = 0; j < 4; ++j) h[j] = fmaxf(acc[i][j] + bb[j], 0.f);
      *(float4*)&Hout[(size_t)row * FD + col0 + tx * 4] = make_float4(h[0], h[1], h[2], h[3]);
      int g = batch[row];
      float* gp = &gsum[(size_t)g * (FD * NLAYERS) + layer * FD + col0 + tx * 4];
      atomicAdd(gp + 0, h[0]);
      atomicAdd(gp + 1, h[1]);
      atomicAdd(gp + 2, h[2]);
      atomicAdd(gp + 3, h[3]);
    }
  }
}

// pooled = gsum/gcnt; logits = pooled @ fcW + fcb; log_softmax. One block per graph.
__global__ void k_fc(const float* __restrict__ gsum, const float* __restrict__ gcnt,
                     const float* __restrict__ fcW, const float* __restrict__ fcb,
                     float* __restrict__ out) {
  int g = blockIdx.x;
  int t = threadIdx.x;  // 64 threads
  __shared__ float logits[NCLS];
  float inv = 1.f / fmaxf(gcnt[g], 1.f);
  for (int c = 0; c < NCLS; ++c) {
    float s = 0.f;
#pragma unroll
    for (int m = 0; m < 8; ++m) {
      int f = t + 64 * m;
      s += gsum[(size_t)g * (FD * NLAYERS) + f] * fcW[(size_t)f * NCLS + c];
    }
    for (int off = 32; off > 0; off >>= 1) s += __shfl_down(s, off);
    if (t == 0) logits[c] = s * inv + fcb[c];
  }
  __syncthreads();
  if (t == 0) {
    float mx = logits[0];
    for (int c = 1; c < NCLS; ++c) mx = fmaxf(mx, logits[c]);
    float se = 0.f;
    for (int c = 0; c < NCLS; ++c) se += expf(logits[c] - mx);
    float lse = mx + logf(se);
    for (int c = 0; c < NCLS; ++c) out[(size_t)g * NCLS + c] = logits[c] - lse;
  }
}

// ---------------- host ----------------
extern "C" void kernel_launch(void* const* d_in, const int* in_sizes, int n_in,
                              void* d_out, int out_size, void* d_ws, size_t ws_size,
                              hipStream_t stream) {
  const float* x      = (const float*)d_in[0];
  const int*   ei     = (const int*)d_in[1];
  const int*   batch  = (const int*)d_in[3];
  const float* W1     = (const float*)d_in[4];
  const float* b1     = (const float*)d_in[5];
  const float* gamma1 = (const float*)d_in[6];
  const float* beta1  = (const float*)d_in[7];
  const float* W2     = (const float*)d_in[8];
  const float* b2     = (const float*)d_in[9];
  const float* fcW    = (const float*)d_in[10];
  const float* fcb    = (const float*)d_in[11];
  float* out = (float*)d_out;

  char* p = (char*)d_ws;
  auto alloc = [&](size_t bytes) {
    char* r = p;
    p += (bytes + 255) & ~(size_t)255;
    return r;
  };
  float* hbuf    = (float*)alloc((size_t)NN * FD * 4);
  float* tbuf    = (float*)alloc((size_t)NN * FD * 4);
  float* Zbuf    = (float*)alloc((size_t)NN * HD2 * 4);
  float* inv_deg = (float*)alloc((size_t)NN * 4);
  float* bnsum   = (float*)alloc(2 * HD2 * 4);
  float* a12     = (float*)alloc(2 * HD2 * 4);
  float* gsum    = (float*)alloc((size_t)NGR * FD * NLAYERS * 4);
  float* gcnt    = (float*)alloc((size_t)NGR * 4);
  int* degi      = (int*)alloc((size_t)NN * 4);
  int* rowptr    = (int*)alloc((size_t)(NN + 1) * 4);
  int* cursor    = (int*)alloc((size_t)NN * 4);
  int* csr       = (int*)alloc((size_t)NE * 4);
  int* bsum      = (int*)alloc(512 * 4);
  int* src32     = (int*)alloc((size_t)NE * 4);
  int* dst32     = (int*)alloc((size_t)NE * 4);
  int* batch32   = (int*)alloc((size_t)NN * 4);
  int* flag      = (int*)alloc(256);

  const int EB = (NE + 255) / 256;   // 6250
  const int NB = (NN + 255) / 256;   // 391

  k_detect<<<1, 256, 0, stream>>>(ei, flag);
  k_repack<<<EB, 256, 0, stream>>>(ei, batch, flag, src32, dst32, batch32);
  k_init<<<(NGR * FD * NLAYERS + 255) / 256, 256, 0, stream>>>(degi, gcnt, gsum);
  k_deg_gcnt<<<EB, 256, 0, stream>>>(dst32, degi, batch32, gcnt);
  k_scan1<<<NB, 256, 0, stream>>>(degi, rowptr, bsum);
  k_scan2<<<1, 512, 0, stream>>>(bsum, NB);
  k_scan3_cursor<<<NB, 256, 0, stream>>>(rowptr, bsum, cursor, degi, inv_deg);
  k_scatter<<<EB, 256, 0, stream>>>(src32, dst32, cursor, csr);

  const float* hin = x;
  const int MB = (NN + 63) / 64;     // 1563
  for (int L = 0; L < NLAYERS; ++L) {
    k_agg<<<(NN + 1) / 2, 256, 0, stream>>>(hin, rowptr, csr, inv_deg, tbuf, bnsum);
    k_gemm1<<<dim3(MB, HD2 / 64), 256, 0, stream>>>(tbuf, W1 + (size_t)L * FD * HD2,
                                                    b1 + (size_t)L * HD2, Zbuf, bnsum);
    k_bnfin<<<1, 256, 0, stream>>>(bnsum, gamma1 + (size_t)L * HD2, beta1 + (size_t)L * HD2, a12);
    k_gemm2<<<dim3(MB, FD / 64), 256, 0, stream>>>(Zbuf, W2 + (size_t)L * HD2 * FD,
                                                   b2 + (size_t)L * FD, a12, batch32,
                                                   hbuf, gsum, L);
    hin = hbuf;
  }
  k_fc<<<NGR, 64, 0, stream>>>(gsum, gcnt, fcW, fcb, out);
}

// Round 3
// 1289.144 us; speedup vs baseline: 2.7039x; 2.7039x over previous
//
#include <hip/hip_runtime.h>
#include <cstdint>
#include <cstddef>

#define NN 100000      // nodes
#define NE 1600000     // edges
#define FD 128         // feature dim
#define HD2 256        // hidden*2
#define NLAYERS 4
#define NGR 512        // graphs
#define NCLS 10
#define BNEPS 1e-5f
#define G1TILES 1563   // ceil(NN/64)
#define GEMM_GRID 521  // 1563 = 3*521

typedef unsigned short ushort_t;
typedef short bf16x8 __attribute__((ext_vector_type(8)));
typedef float f32x4 __attribute__((ext_vector_type(4)));

__device__ __forceinline__ float bfl(unsigned short u) {
  unsigned v = ((unsigned)u) << 16;
  return __builtin_bit_cast(float, v);
}
__device__ __forceinline__ unsigned short fbf(float f) {
  unsigned u = __builtin_bit_cast(unsigned, f);
  unsigned r = (u + 0x7FFFu + ((u >> 16) & 1u)) >> 16;
  return (unsigned short)r;
}

// ---------------- index dtype normalization ----------------
__global__ void k_detect(const int* ei, int* flag) {
  __shared__ int nz;
  if (threadIdx.x == 0) nz = 0;
  __syncthreads();
  if (ei[2 * threadIdx.x + 1] != 0) atomicAdd(&nz, 1);
  __syncthreads();
  if (threadIdx.x == 0) flag[0] = (nz == 0) ? 1 : 0;  // 1 => int64
}

__global__ void k_repack(const int* ei, const int* batch, const int* flag,
                         int* src32, int* dst32, int* batch32) {
  int i = blockIdx.x * 256 + threadIdx.x;
  const bool wide = (flag[0] != 0);
  if (i < NE) {
    src32[i] = wide ? ei[2 * i] : ei[i];
    dst32[i] = wide ? ei[2 * (NE + i)] : ei[NE + i];
  }
  if (i < NN) batch32[i] = wide ? batch[2 * i] : batch[i];
}

// ---------------- setup ----------------
__global__ void k_init(int* degi, int* gcnti, int* gstart) {
  int i = blockIdx.x * 256 + threadIdx.x;
  if (i < NN) degi[i] = 0;
  if (i < NGR) { gcnti[i] = 0; gstart[i] = NN; }
}

__global__ void k_deg_gcnt(const int* dst, int* degi, const int* batch,
                           int* gcnti, int* gstart) {
  int i = blockIdx.x * 256 + threadIdx.x;
  if (i < NE) atomicAdd(&degi[dst[i]], 1);
  if (i < NN) {
    atomicAdd(&gcnti[batch[i]], 1);
    atomicMin(&gstart[batch[i]], i);
  }
}

__global__ void k_scan1(const int* degi, int* rowptr, int* bsum) {
  __shared__ int s[256];
  int t = threadIdx.x;
  int i = blockIdx.x * 256 + t;
  int v = (i < NN) ? degi[i] : 0;
  s[t] = v;
  __syncthreads();
  for (int off = 1; off < 256; off <<= 1) {
    int x = (t >= off) ? s[t - off] : 0;
    __syncthreads();
    s[t] += x;
    __syncthreads();
  }
  if (i < NN) rowptr[i] = s[t] - v;
  if (t == 255) bsum[blockIdx.x] = s[255];
}

__global__ void k_scan2(int* bsum, int nb) {
  __shared__ int s[512];
  int t = threadIdx.x;
  int v = (t < nb) ? bsum[t] : 0;
  s[t] = v;
  __syncthreads();
  for (int off = 1; off < 512; off <<= 1) {
    int x = (t >= off) ? s[t - off] : 0;
    __syncthreads();
    s[t] += x;
    __syncthreads();
  }
  if (t < nb) bsum[t] = s[t] - v;
}

__global__ void k_scan3_cursor(int* rowptr, const int* bsum, int* cursor,
                               const int* degi, float* inv_deg) {
  int i = blockIdx.x * 256 + threadIdx.x;
  if (i < NN) {
    int r = rowptr[i] + bsum[blockIdx.x];
    rowptr[i] = r;
    cursor[i] = r;
    inv_deg[i] = 1.f / fmaxf((float)degi[i], 1.f);
  }
  if (i == 0) rowptr[NN] = NE;
}

__global__ void k_scatter(const int* src, const int* dst, int* cursor, int* csr) {
  int e = blockIdx.x * 256 + threadIdx.x;
  if (e < NE) {
    int p = atomicAdd(&cursor[dst[e]], 1);
    csr[p] = src[e];
  }
}

// ---------------- dtype conversions ----------------
__global__ void k_cvt_x(const float* __restrict__ x, ushort_t* __restrict__ xb) {
  int i = blockIdx.x * 256 + threadIdx.x;  // chunk of 8, 1.6M chunks exactly
  if (i >= NN * FD / 8) return;
  const float4* p = (const float4*)x + (size_t)i * 2;
  float4 a = p[0], b = p[1];
  bf16x8 o;
  o[0] = (short)fbf(a.x); o[1] = (short)fbf(a.y);
  o[2] = (short)fbf(a.z); o[3] = (short)fbf(a.w);
  o[4] = (short)fbf(b.x); o[5] = (short)fbf(b.y);
  o[6] = (short)fbf(b.z); o[7] = (short)fbf(b.w);
  *(bf16x8*)&xb[(size_t)i * 8] = o;
}

// W1 [L][128][256] -> W1t [L][256][128]; W2 [L][256][128] -> W2t [L][128][256]
__global__ void k_cvt_w(const float* __restrict__ W1, const float* __restrict__ W2,
                        ushort_t* __restrict__ W1t, ushort_t* __restrict__ W2t) {
  int idx = blockIdx.x * 256 + threadIdx.x;  // < 131072
  if (idx >= NLAYERS * FD * HD2) return;
  int l = idx >> 15, r = idx & 32767;
  {
    int n = r >> 7, k = r & 127;  // n<256, k<128
    W1t[(size_t)l * 32768 + n * 128 + k] = fbf(W1[(size_t)l * 32768 + k * 256 + n]);
  }
  {
    int n = r >> 8, k = r & 255;  // n<128, k<256
    W2t[(size_t)l * 32768 + n * 256 + k] = fbf(W2[(size_t)l * 32768 + k * 128 + n]);
  }
}

// ---------------- aggregation (bf16 in/out) ----------------
// one wave per node: lane l handles features 2l, 2l+1
__global__ void k_agg(const ushort_t* __restrict__ h, const int* __restrict__ rowptr,
                      const int* __restrict__ csr, const float* __restrict__ inv_deg,
                      ushort_t* __restrict__ tout, float* bnsum) {
  if (blockIdx.x == 0) {  // zero BN accumulators for this layer
    bnsum[threadIdx.x] = 0.f;
    bnsum[HD2 + threadIdx.x] = 0.f;
  }
  int node = blockIdx.x * 4 + (threadIdx.x >> 6);
  if (node >= NN) return;
  int l = threadIdx.x & 63;
  const unsigned* h2 = (const unsigned*)h;  // bf16 pairs
  int beg = rowptr[node], end = rowptr[node + 1];
  float ax = 0.f, ay = 0.f;
  for (int j = beg; j < end; ++j) {
    int s = csr[j];  // uniform across wave -> scalar broadcast
    unsigned p = h2[(size_t)s * 64 + l];
    ax += bfl((unsigned short)(p & 0xFFFF));
    ay += bfl((unsigned short)(p >> 16));
  }
  float id = inv_deg[node];
  unsigned pc = h2[(size_t)node * 64 + l];
  float ox = bfl((unsigned short)(pc & 0xFFFF)) + ax * id;
  float oy = bfl((unsigned short)(pc >> 16)) + ay * id;
  unsigned ow = (unsigned)fbf(ox) | ((unsigned)fbf(oy) << 16);
  ((unsigned*)tout)[(size_t)node * 64 + l] = ow;
}

// ---------------- GEMM1 (MFMA): Z = A @ W1 + b1, bf16 in/out ----------------
// A [NN,128] bf16, Bt = W1^T [256 n][128 k] bf16 fully in LDS.
__launch_bounds__(256, 2)
__global__ void k_gemm1(const ushort_t* __restrict__ A, const ushort_t* __restrict__ Bt,
                        const float* __restrict__ bias, ushort_t* __restrict__ Z) {
  __shared__ ushort_t Bs[256 * 128];  // 64KB, swizzled
  __shared__ ushort_t As[64 * 128];   // 16KB, swizzled
  const int tid = threadIdx.x;
  // stage whole B panel (swizzled): 4096 16B-chunks
#pragma unroll
  for (int i = 0; i < 16; ++i) {
    int chunk = tid + 256 * i;
    int n = chunk >> 4, c = chunk & 15;
    bf16x8 v = *(const bf16x8*)&Bt[n * 128 + c * 8];
    *(bf16x8*)((char*)Bs + n * 256 + ((c * 16) ^ ((n & 7) << 4))) = v;
  }
  const int wv = tid >> 6, ln = tid & 63;
  const int lr = ln & 15, lg = ln >> 4;
  float bb[16];
#pragma unroll
  for (int nt = 0; nt < 16; ++nt) bb[nt] = bias[nt * 16 + lr];

  for (int t = blockIdx.x; t < G1TILES; t += GEMM_GRID) {
    int row0 = t * 64;
    // stage A tile 64x128 (swizzled)
#pragma unroll
    for (int i = 0; i < 4; ++i) {
      int chunk = tid + 256 * i;
      int r = chunk >> 4, c = chunk & 15;
      int grow = row0 + r; if (grow >= NN) grow = NN - 1;
      bf16x8 v = *(const bf16x8*)&A[(size_t)grow * FD + c * 8];
      *(bf16x8*)((char*)As + r * 256 + ((c * 16) ^ ((r & 7) << 4))) = v;
    }
    __syncthreads();
    int arow = wv * 16 + lr;
    bf16x8 af[4];
#pragma unroll
    for (int ks = 0; ks < 4; ++ks)
      af[ks] = *(bf16x8*)((char*)As + arow * 256 + ((ks * 64 + lg * 16) ^ ((arow & 7) << 4)));
    f32x4 acc[16];
#pragma unroll
    for (int nt = 0; nt < 16; ++nt) acc[nt] = (f32x4){0.f, 0.f, 0.f, 0.f};
#pragma unroll
    for (int nt = 0; nt < 16; ++nt) {
      int bn = nt * 16 + lr;
#pragma unroll
      for (int ks = 0; ks < 4; ++ks) {
        bf16x8 bfr = *(bf16x8*)((char*)Bs + bn * 256 + ((ks * 64 + lg * 16) ^ ((bn & 7) << 4)));
        acc[nt] = __builtin_amdgcn_mfma_f32_16x16x32_bf16(af[ks], bfr, acc[nt], 0, 0, 0);
      }
    }
    __syncthreads();
    // epilogue: bias, store bf16
#pragma unroll
    for (int nt = 0; nt < 16; ++nt) {
      int col = nt * 16 + lr;
#pragma unroll
      for (int j = 0; j < 4; ++j) {
        int grow = row0 + wv * 16 + lg * 4 + j;
        if (grow < NN) Z[(size_t)grow * HD2 + col] = fbf(acc[nt][j] + bb[nt]);
      }
    }
  }
}

// ---------------- BN stats over bf16 Z ----------------
__global__ void k_bnstat(const ushort_t* __restrict__ Z, float* __restrict__ bnsum) {
  __shared__ float ls[2 * HD2];
  int t = threadIdx.x;
  ls[t] = 0.f; ls[HD2 + t] = 0.f;
  __syncthreads();
  int c = (t & 31) * 8, ro = t >> 5;
  int base = blockIdx.x * 256;
  float s0[8] = {}, s1[8] = {};
  for (int i = 0; i < 32; ++i) {
    int r = base + ro + 8 * i;
    if (r < NN) {
      bf16x8 v = *(const bf16x8*)&Z[(size_t)r * HD2 + c];
#pragma unroll
      for (int j = 0; j < 8; ++j) {
        float f = bfl((unsigned short)v[j]);
        s0[j] += f; s1[j] += f * f;
      }
    }
  }
#pragma unroll
  for (int j = 0; j < 8; ++j) {
    atomicAdd(&ls[c + j], s0[j]);
    atomicAdd(&ls[HD2 + c + j], s1[j]);
  }
  __syncthreads();
  atomicAdd(&bnsum[t], ls[t]);
  atomicAdd(&bnsum[HD2 + t], ls[HD2 + t]);
}

__global__ void k_bnfin(const float* bnsum, const float* gamma, const float* beta, float* a12) {
  int c = threadIdx.x;
  if (c < HD2) {
    float mu = bnsum[c] * (1.f / (float)NN);
    float var = fmaxf(bnsum[HD2 + c] * (1.f / (float)NN) - mu * mu, 0.f);
    float rs = rsqrtf(var + BNEPS);
    float g = gamma[c] * rs;
    a12[c] = g;
    a12[HD2 + c] = beta[c] - mu * g;
  }
}

// ---------------- GEMM2 (MFMA): H = relu( relu(BN(Z)) @ W2 + b2 ) ----------------
// Z [NN,256] bf16, Bt = W2^T [128 n][256 k] bf16 in LDS; A staged in K-halves.
__launch_bounds__(256, 2)
__global__ void k_gemm2(const ushort_t* __restrict__ Zin, const ushort_t* __restrict__ Bt,
                        const float* __restrict__ bias, const float* __restrict__ a12,
                        ushort_t* __restrict__ Hout) {
  __shared__ ushort_t Bs[128 * 256];  // 64KB swizzled, row len 512B
  __shared__ ushort_t As[64 * 128];   // 16KB swizzled (one K-half)
  const int tid = threadIdx.x;
#pragma unroll
  for (int i = 0; i < 16; ++i) {
    int chunk = tid + 256 * i;       // 4096 chunks
    int n = chunk >> 5, c = chunk & 31;
    bf16x8 v = *(const bf16x8*)&Bt[n * 256 + c * 8];
    *(bf16x8*)((char*)Bs + n * 512 + ((c * 16) ^ ((n & 7) << 4))) = v;
  }
  const int wv = tid >> 6, ln = tid & 63;
  const int lr = ln & 15, lg = ln >> 4;
  // preload BN affine for this thread's staged k-positions
  float a1v[2][8], a2v[2][8];
#pragma unroll
  for (int h = 0; h < 2; ++h)
#pragma unroll
    for (int j = 0; j < 8; ++j) {
      int k = h * 128 + (tid & 15) * 8 + j;
      a1v[h][j] = a12[k];
      a2v[h][j] = a12[HD2 + k];
    }
  float bb[8];
#pragma unroll
  for (int nt = 0; nt < 8; ++nt) bb[nt] = bias[nt * 16 + lr];

  for (int t = blockIdx.x; t < G1TILES; t += GEMM_GRID) {
    int row0 = t * 64;
    f32x4 acc[8];
#pragma unroll
    for (int nt = 0; nt < 8; ++nt) acc[nt] = (f32x4){0.f, 0.f, 0.f, 0.f};
#pragma unroll
    for (int h = 0; h < 2; ++h) {
      // stage A half (affine+relu applied), 1024 chunks
#pragma unroll
      for (int i = 0; i < 4; ++i) {
        int chunk = tid + 256 * i;
        int r = chunk >> 4, c = chunk & 15;
        int grow = row0 + r; if (grow >= NN) grow = NN - 1;
        bf16x8 v = *(const bf16x8*)&Zin[(size_t)grow * HD2 + h * 128 + c * 8];
        bf16x8 o;
#pragma unroll
        for (int j = 0; j < 8; ++j) {
          float f = bfl((unsigned short)v[j]) * a1v[h][j] + a2v[h][j];
          o[j] = (short)fbf(fmaxf(f, 0.f));
        }
        *(bf16x8*)((char*)As + r * 256 + ((c * 16) ^ ((r & 7) << 4))) = o;
      }
      __syncthreads();
      int arow = wv * 16 + lr;
      bf16x8 af[4];
#pragma unroll
      for (int ks = 0; ks < 4; ++ks)
        af[ks] = *(bf16x8*)((char*)As + arow * 256 + ((ks * 64 + lg * 16) ^ ((arow & 7) << 4)));
#pragma unroll
      for (int nt = 0; nt < 8; ++nt) {
        int bn = nt * 16 + lr;
#pragma unroll
        for (int ks = 0; ks < 4; ++ks) {
          bf16x8 bfr = *(bf16x8*)((char*)Bs + bn * 512 +
                                  (((h * 16 + ks * 4 + lg) * 16) ^ ((bn & 7) << 4)));
          acc[nt] = __builtin_amdgcn_mfma_f32_16x16x32_bf16(af[ks], bfr, acc[nt], 0, 0, 0);
        }
      }
      __syncthreads();
    }
#pragma unroll
    for (int nt = 0; nt < 8; ++nt) {
      int col = nt * 16 + lr;
#pragma unroll
      for (int j = 0; j < 4; ++j) {
        int grow = row0 + wv * 16 + lg * 4 + j;
        if (grow < NN) Hout[(size_t)grow * FD + col] = fbf(fmaxf(acc[nt][j] + bb[nt], 0.f));
      }
    }
  }
}

// ---------------- fused pool + FC + log_softmax (one block per graph) ----------------
__launch_bounds__(256)
__global__ void k_pool_fc(const ushort_t* __restrict__ hb, const int* __restrict__ gstart,
                          const int* __restrict__ gcnti, const float* __restrict__ fcW,
                          const float* __restrict__ fcb, float* __restrict__ out) {
  __shared__ float pool4[4][512];
  __shared__ float wred[4][NCLS];
  int g = blockIdx.x, t = threadIdx.x;
  int start = gstart[g], cnt = gcnti[g];
  int chunk = t & 63, ro = t >> 6;
  int L = chunk >> 4, cc = (chunk & 15) * 8;
  const ushort_t* hL = hb + (size_t)L * NN * FD;
  float s[8] = {};
  for (int r = start + ro; r < start + cnt; r += 4) {
    bf16x8 v = *(const bf16x8*)&hL[(size_t)r * FD + cc];
#pragma unroll
    for (int j = 0; j < 8; ++j) s[j] += bfl((unsigned short)v[j]);
  }
#pragma unroll
  for (int j = 0; j < 8; ++j) pool4[ro][chunk * 8 + j] = s[j];
  __syncthreads();
  float inv = 1.f / fmaxf((float)cnt, 1.f);
  float pA = (pool4[0][t] + pool4[1][t] + pool4[2][t] + pool4[3][t]) * inv;
  float pB = (pool4[0][t + 256] + pool4[1][t + 256] + pool4[2][t + 256] + pool4[3][t + 256]) * inv;
  float pacc[NCLS];
#pragma unroll
  for (int c = 0; c < NCLS; ++c)
    pacc[c] = pA * fcW[t * NCLS + c] + pB * fcW[(t + 256) * NCLS + c];
#pragma unroll
  for (int off = 32; off > 0; off >>= 1)
#pragma unroll
    for (int c = 0; c < NCLS; ++c) pacc[c] += __shfl_down(pacc[c], off);
  if ((t & 63) == 0)
#pragma unroll
    for (int c = 0; c < NCLS; ++c) wred[t >> 6][c] = pacc[c];
  __syncthreads();
  if (t == 0) {
    float lg[NCLS];
    float mx = -1e30f;
#pragma unroll
    for (int c = 0; c < NCLS; ++c) {
      lg[c] = wred[0][c] + wred[1][c] + wred[2][c] + wred[3][c] + fcb[c];
      mx = fmaxf(mx, lg[c]);
    }
    float se = 0.f;
#pragma unroll
    for (int c = 0; c < NCLS; ++c) se += expf(lg[c] - mx);
    float lse = mx + logf(se);
#pragma unroll
    for (int c = 0; c < NCLS; ++c) out[(size_t)g * NCLS + c] = lg[c] - lse;
  }
}

// ---------------- host ----------------
extern "C" void kernel_launch(void* const* d_in, const int* in_sizes, int n_in,
                              void* d_out, int out_size, void* d_ws, size_t ws_size,
                              hipStream_t stream) {
  const float* x      = (const float*)d_in[0];
  const int*   ei     = (const int*)d_in[1];
  const int*   batch  = (const int*)d_in[3];
  const float* W1     = (const float*)d_in[4];
  const float* b1     = (const float*)d_in[5];
  const float* gamma1 = (const float*)d_in[6];
  const float* beta1  = (const float*)d_in[7];
  const float* W2     = (const float*)d_in[8];
  const float* b2     = (const float*)d_in[9];
  const float* fcW    = (const float*)d_in[10];
  const float* fcb    = (const float*)d_in[11];
  float* out = (float*)d_out;

  char* p = (char*)d_ws;
  auto alloc = [&](size_t bytes) {
    char* r = p;
    p += (bytes + 255) & ~(size_t)255;
    return r;
  };
  ushort_t* xbf   = (ushort_t*)alloc((size_t)NN * FD * 2);
  ushort_t* tbuf  = (ushort_t*)alloc((size_t)NN * FD * 2);
  ushort_t* Zbuf  = (ushort_t*)alloc((size_t)NN * HD2 * 2);
  ushort_t* hb    = (ushort_t*)alloc((size_t)NLAYERS * NN * FD * 2);
  ushort_t* W1t   = (ushort_t*)alloc((size_t)NLAYERS * FD * HD2 * 2);
  ushort_t* W2t   = (ushort_t*)alloc((size_t)NLAYERS * FD * HD2 * 2);
  float* inv_deg  = (float*)alloc((size_t)NN * 4);
  float* bnsum    = (float*)alloc(2 * HD2 * 4);
  float* a12      = (float*)alloc(2 * HD2 * 4);
  int* degi       = (int*)alloc((size_t)NN * 4);
  int* rowptr     = (int*)alloc((size_t)(NN + 1) * 4);
  int* cursor     = (int*)alloc((size_t)NN * 4);
  int* csr        = (int*)alloc((size_t)NE * 4);
  int* bsum       = (int*)alloc(512 * 4);
  int* src32      = (int*)alloc((size_t)NE * 4);
  int* dst32      = (int*)alloc((size_t)NE * 4);
  int* batch32    = (int*)alloc((size_t)NN * 4);
  int* gcnti      = (int*)alloc((size_t)NGR * 4);
  int* gstart     = (int*)alloc((size_t)NGR * 4);
  int* flag       = (int*)alloc(256);

  const int EB = (NE + 255) / 256;
  const int NB = (NN + 255) / 256;

  k_detect<<<1, 256, 0, stream>>>(ei, flag);
  k_repack<<<EB, 256, 0, stream>>>(ei, batch, flag, src32, dst32, batch32);
  k_init<<<NB, 256, 0, stream>>>(degi, gcnti, gstart);
  k_deg_gcnt<<<EB, 256, 0, stream>>>(dst32, degi, batch32, gcnti, gstart);
  k_scan1<<<NB, 256, 0, stream>>>(degi, rowptr, bsum);
  k_scan2<<<1, 512, 0, stream>>>(bsum, NB);
  k_scan3_cursor<<<NB, 256, 0, stream>>>(rowptr, bsum, cursor, degi, inv_deg);
  k_scatter<<<EB, 256, 0, stream>>>(src32, dst32, cursor, csr);
  k_cvt_x<<<(NN * FD / 8 + 255) / 256, 256, 0, stream>>>(x, xbf);
  k_cvt_w<<<(NLAYERS * FD * HD2 + 255) / 256, 256, 0, stream>>>(W1, W2, W1t, W2t);

  const ushort_t* hin = xbf;
  for (int L = 0; L < NLAYERS; ++L) {
    k_agg<<<NN / 4, 256, 0, stream>>>(hin, rowptr, csr, inv_deg, tbuf, bnsum);
    k_gemm1<<<GEMM_GRID, 256, 0, stream>>>(tbuf, W1t + (size_t)L * FD * HD2,
                                           b1 + (size_t)L * HD2, Zbuf);
    k_bnstat<<<(NN + 255) / 256, 256, 0, stream>>>(Zbuf, bnsum);
    k_bnfin<<<1, 256, 0, stream>>>(bnsum, gamma1 + (size_t)L * HD2, beta1 + (size_t)L * HD2, a12);
    k_gemm2<<<GEMM_GRID, 256, 0, stream>>>(Zbuf, W2t + (size_t)L * FD * HD2,
                                           b2 + (size_t)L * FD, a12,
                                           hb + (size_t)L * NN * FD);
    hin = hb + (size_t)L * NN * FD;
  }
  k_pool_fc<<<NGR, 256, 0, stream>>>(hb, gstart, gcnti, fcW, fcb, out);
}

// Round 6
// 1242.924 us; speedup vs baseline: 2.8045x; 1.0372x over previous
//
#include <hip/hip_runtime.h>
#include <cstdint>
#include <cstddef>

#define NN 100000      // nodes
#define NE 1600000     // edges
#define FD 128         // feature dim
#define HD2 256        // hidden*2
#define NLAYERS 4
#define NGR 512        // graphs
#define NCLS 10
#define BNEPS 1e-5f
#define G1TILES 1563   // ceil(NN/64)
#define GEMM_GRID 521  // 1563 = 3*521

typedef unsigned short ushort_t;
typedef short bf16x8 __attribute__((ext_vector_type(8)));
typedef float f32x4 __attribute__((ext_vector_type(4)));

__device__ __forceinline__ float bfl(unsigned short u) {
  unsigned v = ((unsigned)u) << 16;
  return __builtin_bit_cast(float, v);
}
__device__ __forceinline__ unsigned short fbf(float f) {
  unsigned u = __builtin_bit_cast(unsigned, f);
  unsigned r = (u + 0x7FFFu + ((u >> 16) & 1u)) >> 16;
  return (unsigned short)r;
}

// ---------------- index dtype normalization ----------------
__global__ void k_detect(const int* ei, int* flag) {
  __shared__ int nz;
  if (threadIdx.x == 0) nz = 0;
  __syncthreads();
  if (ei[2 * threadIdx.x + 1] != 0) atomicAdd(&nz, 1);
  __syncthreads();
  if (threadIdx.x == 0) flag[0] = (nz == 0) ? 1 : 0;  // 1 => int64
}

__global__ void k_repack(const int* ei, const int* batch, const int* flag,
                         int* src32, int* dst32, int* batch32) {
  int i = blockIdx.x * 256 + threadIdx.x;
  const bool wide = (flag[0] != 0);
  if (i < NE) {
    src32[i] = wide ? ei[2 * i] : ei[i];
    dst32[i] = wide ? ei[2 * (NE + i)] : ei[NE + i];
  }
  if (i < NN) batch32[i] = wide ? batch[2 * i] : batch[i];
}

// ---------------- setup ----------------
__global__ void k_init(int* degi) {
  int i = blockIdx.x * 256 + threadIdx.x;
  if (i < NN) degi[i] = 0;
}

// edge-degree histogram: random addresses over 400KB -> low contention
__global__ void k_deg(const int* dst, int* degi) {
  int i = blockIdx.x * 256 + threadIdx.x;
  if (i < NE) atomicAdd(&degi[dst[i]], 1);
}

// batch is SORTED -> per-graph start/count via binary search (no atomics)
__global__ void k_gstats(const int* __restrict__ batch, int* __restrict__ gstart,
                         int* __restrict__ gcnti) {
  int g = threadIdx.x;
  if (g >= NGR) return;
  int lo = 0, hi = NN;
  while (lo < hi) { int m = (lo + hi) >> 1; if (batch[m] < g) lo = m + 1; else hi = m; }
  int s = lo;
  hi = NN;
  while (lo < hi) { int m = (lo + hi) >> 1; if (batch[m] < g + 1) lo = m + 1; else hi = m; }
  gstart[g] = s;
  gcnti[g] = lo - s;
}

__global__ void k_scan1(const int* degi, int* rowptr, int* bsum) {
  __shared__ int s[256];
  int t = threadIdx.x;
  int i = blockIdx.x * 256 + t;
  int v = (i < NN) ? degi[i] : 0;
  s[t] = v;
  __syncthreads();
  for (int off = 1; off < 256; off <<= 1) {
    int x = (t >= off) ? s[t - off] : 0;
    __syncthreads();
    s[t] += x;
    __syncthreads();
  }
  if (i < NN) rowptr[i] = s[t] - v;
  if (t == 255) bsum[blockIdx.x] = s[255];
}

__global__ void k_scan2(int* bsum, int nb) {
  __shared__ int s[512];
  int t = threadIdx.x;
  int v = (t < nb) ? bsum[t] : 0;
  s[t] = v;
  __syncthreads();
  for (int off = 1; off < 512; off <<= 1) {
    int x = (t >= off) ? s[t - off] : 0;
    __syncthreads();
    s[t] += x;
    __syncthreads();
  }
  if (t < nb) bsum[t] = s[t] - v;
}

__global__ void k_scan3_cursor(int* rowptr, const int* bsum, int* cursor,
                               const int* degi, float* inv_deg) {
  int i = blockIdx.x * 256 + threadIdx.x;
  if (i < NN) {
    int r = rowptr[i] + bsum[blockIdx.x];
    rowptr[i] = r;
    cursor[i] = r;
    inv_deg[i] = 1.f / fmaxf((float)degi[i], 1.f);
  }
  if (i == 0) rowptr[NN] = NE;
}

__global__ void k_scatter(const int* src, const int* dst, int* cursor, int* csr) {
  int e = blockIdx.x * 256 + threadIdx.x;
  if (e < NE) {
    int p = atomicAdd(&cursor[dst[e]], 1);
    csr[p] = src[e];
  }
}

// ---------------- dtype conversions ----------------
__global__ void k_cvt_x(const float* __restrict__ x, ushort_t* __restrict__ xb) {
  int i = blockIdx.x * 256 + threadIdx.x;  // chunk of 8
  if (i >= NN * FD / 8) return;
  const float4* p = (const float4*)x + (size_t)i * 2;
  float4 a = p[0], b = p[1];
  bf16x8 o;
  o[0] = (short)fbf(a.x); o[1] = (short)fbf(a.y);
  o[2] = (short)fbf(a.z); o[3] = (short)fbf(a.w);
  o[4] = (short)fbf(b.x); o[5] = (short)fbf(b.y);
  o[6] = (short)fbf(b.z); o[7] = (short)fbf(b.w);
  *(bf16x8*)&xb[(size_t)i * 8] = o;
}

// W1 [L][128][256] -> W1t [L][256][128]; W2 [L][256][128] -> W2t [L][128][256]
__global__ void k_cvt_w(const float* __restrict__ W1, const float* __restrict__ W2,
                        ushort_t* __restrict__ W1t, ushort_t* __restrict__ W2t) {
  int idx = blockIdx.x * 256 + threadIdx.x;  // < 131072
  if (idx >= NLAYERS * FD * HD2) return;
  int l = idx >> 15, r = idx & 32767;
  {
    int n = r >> 7, k = r & 127;
    W1t[(size_t)l * 32768 + n * 128 + k] = fbf(W1[(size_t)l * 32768 + k * 256 + n]);
  }
  {
    int n = r >> 8, k = r & 255;
    W2t[(size_t)l * 32768 + n * 256 + k] = fbf(W2[(size_t)l * 32768 + k * 128 + n]);
  }
}

// ---------------- aggregation (bf16 in/out) ----------------
__global__ void k_agg(const ushort_t* __restrict__ h, const int* __restrict__ rowptr,
                      const int* __restrict__ csr, const float* __restrict__ inv_deg,
                      ushort_t* __restrict__ tout, float* bnsum) {
  if (blockIdx.x == 0) {  // zero BN accumulators for this layer
    bnsum[threadIdx.x] = 0.f;
    bnsum[HD2 + threadIdx.x] = 0.f;
  }
  int node = blockIdx.x * 4 + (threadIdx.x >> 6);
  if (node >= NN) return;
  int l = threadIdx.x & 63;
  const unsigned* h2 = (const unsigned*)h;  // bf16 pairs
  int beg = rowptr[node], end = rowptr[node + 1];
  float ax = 0.f, ay = 0.f;
  for (int j = beg; j < end; ++j) {
    int s = csr[j];
    unsigned p = h2[(size_t)s * 64 + l];
    ax += bfl((unsigned short)(p & 0xFFFF));
    ay += bfl((unsigned short)(p >> 16));
  }
  float id = inv_deg[node];
  unsigned pc = h2[(size_t)node * 64 + l];
  float ox = bfl((unsigned short)(pc & 0xFFFF)) + ax * id;
  float oy = bfl((unsigned short)(pc >> 16)) + ay * id;
  unsigned ow = (unsigned)fbf(ox) | ((unsigned)fbf(oy) << 16);
  ((unsigned*)tout)[(size_t)node * 64 + l] = ow;
}

// ---------------- GEMM1 (MFMA): Z = A @ W1 + b1, bf16 in/out; fused BN stats ----------------
__launch_bounds__(256, 2)
__global__ void k_gemm1(const ushort_t* __restrict__ A, const ushort_t* __restrict__ Bt,
                        const float* __restrict__ bias, ushort_t* __restrict__ Z,
                        float* __restrict__ bnsum) {
  __shared__ ushort_t Bs[256 * 128];  // 64KB, swizzled
  __shared__ ushort_t As[64 * 128];   // 16KB, swizzled (reused for stat reduce at end)
  const int tid = threadIdx.x;
#pragma unroll
  for (int i = 0; i < 16; ++i) {
    int chunk = tid + 256 * i;
    int n = chunk >> 4, c = chunk & 15;
    bf16x8 v = *(const bf16x8*)&Bt[n * 128 + c * 8];
    *(bf16x8*)((char*)Bs + n * 256 + ((c * 16) ^ ((n & 7) << 4))) = v;
  }
  const int wv = tid >> 6, ln = tid & 63;
  const int lr = ln & 15, lg = ln >> 4;
  float bb[16];
#pragma unroll
  for (int nt = 0; nt < 16; ++nt) bb[nt] = bias[nt * 16 + lr];
  float s0[16] = {}, s1[16] = {};   // per-thread BN partial sums (column nt*16+lr)

  for (int t = blockIdx.x; t < G1TILES; t += GEMM_GRID) {
    int row0 = t * 64;
#pragma unroll
    for (int i = 0; i < 4; ++i) {
      int chunk = tid + 256 * i;
      int r = chunk >> 4, c = chunk & 15;
      int grow = row0 + r; if (grow >= NN) grow = NN - 1;
      bf16x8 v = *(const bf16x8*)&A[(size_t)grow * FD + c * 8];
      *(bf16x8*)((char*)As + r * 256 + ((c * 16) ^ ((r & 7) << 4))) = v;
    }
    __syncthreads();
    int arow = wv * 16 + lr;
    bf16x8 af[4];
#pragma unroll
    for (int ks = 0; ks < 4; ++ks)
      af[ks] = *(bf16x8*)((char*)As + arow * 256 + ((ks * 64 + lg * 16) ^ ((arow & 7) << 4)));
    f32x4 acc[16];
#pragma unroll
    for (int nt = 0; nt < 16; ++nt) acc[nt] = (f32x4){0.f, 0.f, 0.f, 0.f};
#pragma unroll
    for (int nt = 0; nt < 16; ++nt) {
      int bn = nt * 16 + lr;
#pragma unroll
      for (int ks = 0; ks < 4; ++ks) {
        bf16x8 bfr = *(bf16x8*)((char*)Bs + bn * 256 + ((ks * 64 + lg * 16) ^ ((bn & 7) << 4)));
        acc[nt] = __builtin_amdgcn_mfma_f32_16x16x32_bf16(af[ks], bfr, acc[nt], 0, 0, 0);
      }
    }
    __syncthreads();
#pragma unroll
    for (int nt = 0; nt < 16; ++nt) {
      int col = nt * 16 + lr;
#pragma unroll
      for (int j = 0; j < 4; ++j) {
        int grow = row0 + wv * 16 + lg * 4 + j;
        if (grow < NN) {
          unsigned short zb = fbf(acc[nt][j] + bb[nt]);
          Z[(size_t)grow * HD2 + col] = zb;
          float zf = bfl(zb);     // stats on exactly what gemm2 consumes
          s0[nt] += zf;
          s1[nt] += zf * zf;
        }
      }
    }
  }
  // block-level BN stat reduction through As, then distinct-address global atomics
  __syncthreads();
  float* ls = (float*)As;  // ls[0..255]=sum, ls[256..511]=sumsq
  ls[tid] = 0.f; ls[tid + 256] = 0.f;
  __syncthreads();
#pragma unroll
  for (int nt = 0; nt < 16; ++nt) {
    int col = nt * 16 + lr;
    atomicAdd(&ls[col], s0[nt]);
    atomicAdd(&ls[col + 256], s1[nt]);
  }
  __syncthreads();
  if (tid < 256) {
    atomicAdd(&bnsum[tid], ls[tid]);
    atomicAdd(&bnsum[HD2 + tid], ls[tid + 256]);
  }
}

__global__ void k_bnfin(const float* bnsum, const float* gamma, const float* beta, float* a12) {
  int c = threadIdx.x;
  if (c < HD2) {
    float mu = bnsum[c] * (1.f / (float)NN);
    float var = fmaxf(bnsum[HD2 + c] * (1.f / (float)NN) - mu * mu, 0.f);
    float rs = rsqrtf(var + BNEPS);
    float g = gamma[c] * rs;
    a12[c] = g;
    a12[HD2 + c] = beta[c] - mu * g;
  }
}

// ---------------- GEMM2 (MFMA): H = relu( relu(BN(Z)) @ W2 + b2 ) ----------------
__launch_bounds__(256, 2)
__global__ void k_gemm2(const ushort_t* __restrict__ Zin, const ushort_t* __restrict__ Bt,
                        const float* __restrict__ bias, const float* __restrict__ a12,
                        ushort_t* __restrict__ Hout) {
  __shared__ ushort_t Bs[128 * 256];  // 64KB swizzled, row len 512B
  __shared__ ushort_t As[64 * 128];   // 16KB swizzled (one K-half)
  const int tid = threadIdx.x;
#pragma unroll
  for (int i = 0; i < 16; ++i) {
    int chunk = tid + 256 * i;
    int n = chunk >> 5, c = chunk & 31;
    bf16x8 v = *(const bf16x8*)&Bt[n * 256 + c * 8];
    *(bf16x8*)((char*)Bs + n * 512 + ((c * 16) ^ ((n & 7) << 4))) = v;
  }
  const int wv = tid >> 6, ln = tid & 63;
  const int lr = ln & 15, lg = ln >> 4;
  float a1v[2][8], a2v[2][8];
#pragma unroll
  for (int h = 0; h < 2; ++h)
#pragma unroll
    for (int j = 0; j < 8; ++j) {
      int k = h * 128 + (tid & 15) * 8 + j;
      a1v[h][j] = a12[k];
      a2v[h][j] = a12[HD2 + k];
    }
  float bb[8];
#pragma unroll
  for (int nt = 0; nt < 8; ++nt) bb[nt] = bias[nt * 16 + lr];

  for (int t = blockIdx.x; t < G1TILES; t += GEMM_GRID) {
    int row0 = t * 64;
    f32x4 acc[8];
#pragma unroll
    for (int nt = 0; nt < 8; ++nt) acc[nt] = (f32x4){0.f, 0.f, 0.f, 0.f};
#pragma unroll
    for (int h = 0; h < 2; ++h) {
#pragma unroll
      for (int i = 0; i < 4; ++i) {
        int chunk = tid + 256 * i;
        int r = chunk >> 4, c = chunk & 15;
        int grow = row0 + r; if (grow >= NN) grow = NN - 1;
        bf16x8 v = *(const bf16x8*)&Zin[(size_t)grow * HD2 + h * 128 + c * 8];
        bf16x8 o;
#pragma unroll
        for (int j = 0; j < 8; ++j) {
          float f = bfl((unsigned short)v[j]) * a1v[h][j] + a2v[h][j];
          o[j] = (short)fbf(fmaxf(f, 0.f));
        }
        *(bf16x8*)((char*)As + r * 256 + ((c * 16) ^ ((r & 7) << 4))) = o;
      }
      __syncthreads();
      int arow = wv * 16 + lr;
      bf16x8 af[4];
#pragma unroll
      for (int ks = 0; ks < 4; ++ks)
        af[ks] = *(bf16x8*)((char*)As + arow * 256 + ((ks * 64 + lg * 16) ^ ((arow & 7) << 4)));
#pragma unroll
      for (int nt = 0; nt < 8; ++nt) {
        int bn = nt * 16 + lr;
#pragma unroll
        for (int ks = 0; ks < 4; ++ks) {
          bf16x8 bfr = *(bf16x8*)((char*)Bs + bn * 512 +
                                  (((h * 16 + ks * 4 + lg) * 16) ^ ((bn & 7) << 4)));
          acc[nt] = __builtin_amdgcn_mfma_f32_16x16x32_bf16(af[ks], bfr, acc[nt], 0, 0, 0);
        }
      }
      __syncthreads();
    }
#pragma unroll
    for (int nt = 0; nt < 8; ++nt) {
      int col = nt * 16 + lr;
#pragma unroll
      for (int j = 0; j < 4; ++j) {
        int grow = row0 + wv * 16 + lg * 4 + j;
        if (grow < NN) Hout[(size_t)grow * FD + col] = fbf(fmaxf(acc[nt][j] + bb[nt], 0.f));
      }
    }
  }
}

// ---------------- fused pool + FC + log_softmax (one block per graph) ----------------
__launch_bounds__(256)
__global__ void k_pool_fc(const ushort_t* __restrict__ hb, const int* __restrict__ gstart,
                          const int* __restrict__ gcnti, const float* __restrict__ fcW,
                          const float* __restrict__ fcb, float* __restrict__ out) {
  __shared__ float pool4[4][512];
  __shared__ float wred[4][NCLS];
  int g = blockIdx.x, t = threadIdx.x;
  int start = gstart[g], cnt = gcnti[g];
  int chunk = t & 63, ro = t >> 6;
  int L = chunk >> 4, cc = (chunk & 15) * 8;
  const ushort_t* hL = hb + (size_t)L * NN * FD;
  float s[8] = {};
  for (int r = start + ro; r < start + cnt; r += 4) {
    bf16x8 v = *(const bf16x8*)&hL[(size_t)r * FD + cc];
#pragma unroll
    for (int j = 0; j < 8; ++j) s[j] += bfl((unsigned short)v[j]);
  }
#pragma unroll
  for (int j = 0; j < 8; ++j) pool4[ro][chunk * 8 + j] = s[j];
  __syncthreads();
  float inv = 1.f / fmaxf((float)cnt, 1.f);
  float pA = (pool4[0][t] + pool4[1][t] + pool4[2][t] + pool4[3][t]) * inv;
  float pB = (pool4[0][t + 256] + pool4[1][t + 256] + pool4[2][t + 256] + pool4[3][t + 256]) * inv;
  float pacc[NCLS];
#pragma unroll
  for (int c = 0; c < NCLS; ++c)
    pacc[c] = pA * fcW[t * NCLS + c] + pB * fcW[(t + 256) * NCLS + c];
#pragma unroll
  for (int off = 32; off > 0; off >>= 1)
#pragma unroll
    for (int c = 0; c < NCLS; ++c) pacc[c] += __shfl_down(pacc[c], off);
  if ((t & 63) == 0)
#pragma unroll
    for (int c = 0; c < NCLS; ++c) wred[t >> 6][c] = pacc[c];
  __syncthreads();
  if (t == 0) {
    float lg[NCLS];
    float mx = -1e30f;
#pragma unroll
    for (int c = 0; c < NCLS; ++c) {
      lg[c] = wred[0][c] + wred[1][c] + wred[2][c] + wred[3][c] + fcb[c];
      mx = fmaxf(mx, lg[c]);
    }
    float se = 0.f;
#pragma unroll
    for (int c = 0; c < NCLS; ++c) se += expf(lg[c] - mx);
    float lse = mx + logf(se);
#pragma unroll
    for (int c = 0; c < NCLS; ++c) out[(size_t)g * NCLS + c] = lg[c] - lse;
  }
}

// ---------------- host ----------------
extern "C" void kernel_launch(void* const* d_in, const int* in_sizes, int n_in,
                              void* d_out, int out_size, void* d_ws, size_t ws_size,
                              hipStream_t stream) {
  const float* x      = (const float*)d_in[0];
  const int*   ei     = (const int*)d_in[1];
  const int*   batch  = (const int*)d_in[3];
  const float* W1     = (const float*)d_in[4];
  const float* b1     = (const float*)d_in[5];
  const float* gamma1 = (const float*)d_in[6];
  const float* beta1  = (const float*)d_in[7];
  const float* W2     = (const float*)d_in[8];
  const float* b2     = (const float*)d_in[9];
  const float* fcW    = (const float*)d_in[10];
  const float* fcb    = (const float*)d_in[11];
  float* out = (float*)d_out;

  char* p = (char*)d_ws;
  auto alloc = [&](size_t bytes) {
    char* r = p;
    p += (bytes + 255) & ~(size_t)255;
    return r;
  };
  ushort_t* xbf   = (ushort_t*)alloc((size_t)NN * FD * 2);
  ushort_t* tbuf  = (ushort_t*)alloc((size_t)NN * FD * 2);
  ushort_t* Zbuf  = (ushort_t*)alloc((size_t)NN * HD2 * 2);
  ushort_t* hb    = (ushort_t*)alloc((size_t)NLAYERS * NN * FD * 2);
  ushort_t* W1t   = (ushort_t*)alloc((size_t)NLAYERS * FD * HD2 * 2);
  ushort_t* W2t   = (ushort_t*)alloc((size_t)NLAYERS * FD * HD2 * 2);
  float* inv_deg  = (float*)alloc((size_t)NN * 4);
  float* bnsum    = (float*)alloc(2 * HD2 * 4);
  float* a12      = (float*)alloc(2 * HD2 * 4);
  int* degi       = (int*)alloc((size_t)NN * 4);
  int* rowptr     = (int*)alloc((size_t)(NN + 1) * 4);
  int* cursor     = (int*)alloc((size_t)NN * 4);
  int* csr        = (int*)alloc((size_t)NE * 4);
  int* bsum       = (int*)alloc(512 * 4);
  int* src32      = (int*)alloc((size_t)NE * 4);
  int* dst32      = (int*)alloc((size_t)NE * 4);
  int* batch32    = (int*)alloc((size_t)NN * 4);
  int* gcnti      = (int*)alloc((size_t)NGR * 4);
  int* gstart     = (int*)alloc((size_t)NGR * 4);
  int* flag       = (int*)alloc(256);

  const int EB = (NE + 255) / 256;
  const int NB = (NN + 255) / 256;

  k_detect<<<1, 256, 0, stream>>>(ei, flag);
  k_repack<<<EB, 256, 0, stream>>>(ei, batch, flag, src32, dst32, batch32);
  k_init<<<NB, 256, 0, stream>>>(degi);
  k_deg<<<EB, 256, 0, stream>>>(dst32, degi);
  k_gstats<<<1, 512, 0, stream>>>(batch32, gstart, gcnti);
  k_scan1<<<NB, 256, 0, stream>>>(degi, rowptr, bsum);
  k_scan2<<<1, 512, 0, stream>>>(bsum, NB);
  k_scan3_cursor<<<NB, 256, 0, stream>>>(rowptr, bsum, cursor, degi, inv_deg);
  k_scatter<<<EB, 256, 0, stream>>>(src32, dst32, cursor, csr);
  k_cvt_x<<<(NN * FD / 8 + 255) / 256, 256, 0, stream>>>(x, xbf);
  k_cvt_w<<<(NLAYERS * FD * HD2 + 255) / 256, 256, 0, stream>>>(W1, W2, W1t, W2t);

  const ushort_t* hin = xbf;
  for (int L = 0; L < NLAYERS; ++L) {
    k_agg<<<NN / 4, 256, 0, stream>>>(hin, rowptr, csr, inv_deg, tbuf, bnsum);
    k_gemm1<<<GEMM_GRID, 256, 0, stream>>>(tbuf, W1t + (size_t)L * FD * HD2,
                                           b1 + (size_t)L * HD2, Zbuf, bnsum);
    k_bnfin<<<1, 256, 0, stream>>>(bnsum, gamma1 + (size_t)L * HD2, beta1 + (size_t)L * HD2, a12);
    k_gemm2<<<GEMM_GRID, 256, 0, stream>>>(Zbuf, W2t + (size_t)L * FD * HD2,
                                           b2 + (size_t)L * FD, a12,
                                           hb + (size_t)L * NN * FD);
    hin = hb + (size_t)L * NN * FD;
  }
  k_pool_fc<<<NGR, 256, 0, stream>>>(hb, gstart, gcnti, fcW, fcb, out);
}

// Round 7
// 935.233 us; speedup vs baseline: 3.7271x; 1.3290x over previous
//
#include <hip/hip_runtime.h>
#include <cstdint>
#include <cstddef>

#define NN 100000      // nodes
#define NE 1600000     // edges
#define FD 128         // feature dim
#define HD2 256        // hidden*2
#define NLAYERS 4
#define NGR 512        // graphs
#define NCLS 10
#define BNEPS 1e-5f
#define G1TILES 1563   // ceil(NN/64)
#define GEMM_GRID 521  // 1563 = 3*521

typedef unsigned short ushort_t;
typedef short bf16x8 __attribute__((ext_vector_type(8)));
typedef float f32x4 __attribute__((ext_vector_type(4)));

__device__ __forceinline__ float bfl(unsigned short u) {
  unsigned v = ((unsigned)u) << 16;
  return __builtin_bit_cast(float, v);
}
__device__ __forceinline__ unsigned short fbf(float f) {
  unsigned u = __builtin_bit_cast(unsigned, f);
  unsigned r = (u + 0x7FFFu + ((u >> 16) & 1u)) >> 16;
  return (unsigned short)r;
}

// ---------------- index dtype normalization ----------------
__global__ void k_detect(const int* ei, int* flag) {
  __shared__ int nz;
  if (threadIdx.x == 0) nz = 0;
  __syncthreads();
  if (ei[2 * threadIdx.x + 1] != 0) atomicAdd(&nz, 1);
  __syncthreads();
  if (threadIdx.x == 0) flag[0] = (nz == 0) ? 1 : 0;  // 1 => int64
}

__global__ void k_repack(const int* ei, const int* batch, const int* flag,
                         int* src32, int* dst32, int* batch32) {
  int i = blockIdx.x * 256 + threadIdx.x;
  const bool wide = (flag[0] != 0);
  if (i < NE) {
    src32[i] = wide ? ei[2 * i] : ei[i];
    dst32[i] = wide ? ei[2 * (NE + i)] : ei[NE + i];
  }
  if (i < NN) batch32[i] = wide ? batch[2 * i] : batch[i];
}

// ---------------- setup ----------------
__global__ void k_init(int* degi) {
  int i = blockIdx.x * 256 + threadIdx.x;
  if (i < NN) degi[i] = 0;
}

// edge-degree histogram: random addresses over 400KB -> low contention
__global__ void k_deg(const int* dst, int* degi) {
  int i = blockIdx.x * 256 + threadIdx.x;
  if (i < NE) atomicAdd(&degi[dst[i]], 1);
}

// batch is SORTED -> per-graph start/count via binary search (no atomics)
__global__ void k_gstats(const int* __restrict__ batch, int* __restrict__ gstart,
                         int* __restrict__ gcnti) {
  int g = threadIdx.x;
  if (g >= NGR) return;
  int lo = 0, hi = NN;
  while (lo < hi) { int m = (lo + hi) >> 1; if (batch[m] < g) lo = m + 1; else hi = m; }
  int s = lo;
  hi = NN;
  while (lo < hi) { int m = (lo + hi) >> 1; if (batch[m] < g + 1) lo = m + 1; else hi = m; }
  gstart[g] = s;
  gcnti[g] = lo - s;
}

__global__ void k_scan1(const int* degi, int* rowptr, int* bsum) {
  __shared__ int s[256];
  int t = threadIdx.x;
  int i = blockIdx.x * 256 + t;
  int v = (i < NN) ? degi[i] : 0;
  s[t] = v;
  __syncthreads();
  for (int off = 1; off < 256; off <<= 1) {
    int x = (t >= off) ? s[t - off] : 0;
    __syncthreads();
    s[t] += x;
    __syncthreads();
  }
  if (i < NN) rowptr[i] = s[t] - v;
  if (t == 255) bsum[blockIdx.x] = s[255];
}

__global__ void k_scan2(int* bsum, int nb) {
  __shared__ int s[512];
  int t = threadIdx.x;
  int v = (t < nb) ? bsum[t] : 0;
  s[t] = v;
  __syncthreads();
  for (int off = 1; off < 512; off <<= 1) {
    int x = (t >= off) ? s[t - off] : 0;
    __syncthreads();
    s[t] += x;
    __syncthreads();
  }
  if (t < nb) bsum[t] = s[t] - v;
}

__global__ void k_scan3_cursor(int* rowptr, const int* bsum, int* cursor,
                               const int* degi, float* inv_deg) {
  int i = blockIdx.x * 256 + threadIdx.x;
  if (i < NN) {
    int r = rowptr[i] + bsum[blockIdx.x];
    rowptr[i] = r;
    cursor[i] = r;
    inv_deg[i] = 1.f / fmaxf((float)degi[i], 1.f);
  }
  if (i == 0) rowptr[NN] = NE;
}

__global__ void k_scatter(const int* src, const int* dst, int* cursor, int* csr) {
  int e = blockIdx.x * 256 + threadIdx.x;
  if (e < NE) {
    int p = atomicAdd(&cursor[dst[e]], 1);
    csr[p] = src[e];
  }
}

// ---------------- dtype conversions ----------------
__global__ void k_cvt_x(const float* __restrict__ x, ushort_t* __restrict__ xb) {
  int i = blockIdx.x * 256 + threadIdx.x;  // chunk of 8
  if (i >= NN * FD / 8) return;
  const float4* p = (const float4*)x + (size_t)i * 2;
  float4 a = p[0], b = p[1];
  bf16x8 o;
  o[0] = (short)fbf(a.x); o[1] = (short)fbf(a.y);
  o[2] = (short)fbf(a.z); o[3] = (short)fbf(a.w);
  o[4] = (short)fbf(b.x); o[5] = (short)fbf(b.y);
  o[6] = (short)fbf(b.z); o[7] = (short)fbf(b.w);
  *(bf16x8*)&xb[(size_t)i * 8] = o;
}

// W1 [L][128][256] -> W1t [L][256][128]; W2 [L][256][128] -> W2t [L][128][256]
__global__ void k_cvt_w(const float* __restrict__ W1, const float* __restrict__ W2,
                        ushort_t* __restrict__ W1t, ushort_t* __restrict__ W2t) {
  int idx = blockIdx.x * 256 + threadIdx.x;  // < 131072
  if (idx >= NLAYERS * FD * HD2) return;
  int l = idx >> 15, r = idx & 32767;
  {
    int n = r >> 7, k = r & 127;
    W1t[(size_t)l * 32768 + n * 128 + k] = fbf(W1[(size_t)l * 32768 + k * 256 + n]);
  }
  {
    int n = r >> 8, k = r & 255;
    W2t[(size_t)l * 32768 + n * 256 + k] = fbf(W2[(size_t)l * 32768 + k * 128 + n]);
  }
}

// ---------------- aggregation (bf16 in/out), 8-deep MLP unroll ----------------
// one wave per node: lane l handles features 2l, 2l+1 (one dword per row-gather)
__global__ void k_agg(const ushort_t* __restrict__ h, const int* __restrict__ rowptr,
                      const int* __restrict__ csr, const float* __restrict__ inv_deg,
                      ushort_t* __restrict__ tout, float* bnsum) {
  if (blockIdx.x == 0) {  // zero BN accumulators for this layer
    bnsum[threadIdx.x] = 0.f;
    bnsum[HD2 + threadIdx.x] = 0.f;
  }
  int node = blockIdx.x * 4 + (threadIdx.x >> 6);
  if (node >= NN) return;
  int l = threadIdx.x & 63;
  const unsigned* h2 = (const unsigned*)h;  // bf16 pairs
  int beg = rowptr[node], end = rowptr[node + 1];
  float ax = 0.f, ay = 0.f;
  int j = beg;
  // 8 gathers in flight per wave (csr indices are wave-uniform -> scalar loads)
  for (; j + 8 <= end; j += 8) {
    unsigned p[8];
#pragma unroll
    for (int u = 0; u < 8; ++u) {
      int s = csr[j + u];
      p[u] = h2[(size_t)s * 64 + l];
    }
#pragma unroll
    for (int u = 0; u < 8; ++u) {
      ax += bfl((unsigned short)(p[u] & 0xFFFF));
      ay += bfl((unsigned short)(p[u] >> 16));
    }
  }
  for (; j < end; ++j) {
    int s = csr[j];
    unsigned p = h2[(size_t)s * 64 + l];
    ax += bfl((unsigned short)(p & 0xFFFF));
    ay += bfl((unsigned short)(p >> 16));
  }
  float id = inv_deg[node];
  unsigned pc = h2[(size_t)node * 64 + l];
  float ox = bfl((unsigned short)(pc & 0xFFFF)) + ax * id;
  float oy = bfl((unsigned short)(pc >> 16)) + ay * id;
  unsigned ow = (unsigned)fbf(ox) | ((unsigned)fbf(oy) << 16);
  ((unsigned*)tout)[(size_t)node * 64 + l] = ow;
}

// ---------------- GEMM1 (MFMA): Z = A @ W1 + b1, bf16 in/out; fused BN stats ----------------
__launch_bounds__(256, 2)
__global__ void k_gemm1(const ushort_t* __restrict__ A, const ushort_t* __restrict__ Bt,
                        const float* __restrict__ bias, ushort_t* __restrict__ Z,
                        float* __restrict__ bnsum) {
  __shared__ ushort_t Bs[256 * 128];  // 64KB, swizzled
  __shared__ ushort_t As[64 * 128];   // 16KB, swizzled (reused for stat reduce at end)
  const int tid = threadIdx.x;
#pragma unroll
  for (int i = 0; i < 16; ++i) {
    int chunk = tid + 256 * i;
    int n = chunk >> 4, c = chunk & 15;
    bf16x8 v = *(const bf16x8*)&Bt[n * 128 + c * 8];
    *(bf16x8*)((char*)Bs + n * 256 + ((c * 16) ^ ((n & 7) << 4))) = v;
  }
  const int wv = tid >> 6, ln = tid & 63;
  const int lr = ln & 15, lg = ln >> 4;
  float bb[16];
#pragma unroll
  for (int nt = 0; nt < 16; ++nt) bb[nt] = bias[nt * 16 + lr];
  float s0[16] = {}, s1[16] = {};   // per-thread BN partial sums (column nt*16+lr)

  for (int t = blockIdx.x; t < G1TILES; t += GEMM_GRID) {
    int row0 = t * 64;
#pragma unroll
    for (int i = 0; i < 4; ++i) {
      int chunk = tid + 256 * i;
      int r = chunk >> 4, c = chunk & 15;
      int grow = row0 + r; if (grow >= NN) grow = NN - 1;
      bf16x8 v = *(const bf16x8*)&A[(size_t)grow * FD + c * 8];
      *(bf16x8*)((char*)As + r * 256 + ((c * 16) ^ ((r & 7) << 4))) = v;
    }
    __syncthreads();
    int arow = wv * 16 + lr;
    bf16x8 af[4];
#pragma unroll
    for (int ks = 0; ks < 4; ++ks)
      af[ks] = *(bf16x8*)((char*)As + arow * 256 + ((ks * 64 + lg * 16) ^ ((arow & 7) << 4)));
    f32x4 acc[16];
#pragma unroll
    for (int nt = 0; nt < 16; ++nt) acc[nt] = (f32x4){0.f, 0.f, 0.f, 0.f};
#pragma unroll
    for (int nt = 0; nt < 16; ++nt) {
      int bn = nt * 16 + lr;
#pragma unroll
      for (int ks = 0; ks < 4; ++ks) {
        bf16x8 bfr = *(bf16x8*)((char*)Bs + bn * 256 + ((ks * 64 + lg * 16) ^ ((bn & 7) << 4)));
        acc[nt] = __builtin_amdgcn_mfma_f32_16x16x32_bf16(af[ks], bfr, acc[nt], 0, 0, 0);
      }
    }
    __syncthreads();
#pragma unroll
    for (int nt = 0; nt < 16; ++nt) {
      int col = nt * 16 + lr;
#pragma unroll
      for (int j = 0; j < 4; ++j) {
        int grow = row0 + wv * 16 + lg * 4 + j;
        if (grow < NN) {
          unsigned short zb = fbf(acc[nt][j] + bb[nt]);
          Z[(size_t)grow * HD2 + col] = zb;
          float zf = bfl(zb);     // stats on exactly what gemm2 consumes
          s0[nt] += zf;
          s1[nt] += zf * zf;
        }
      }
    }
  }
  // block-level BN stat reduction through As, then distinct-address global atomics
  __syncthreads();
  float* ls = (float*)As;  // ls[0..255]=sum, ls[256..511]=sumsq
  ls[tid] = 0.f; ls[tid + 256] = 0.f;
  __syncthreads();
#pragma unroll
  for (int nt = 0; nt < 16; ++nt) {
    int col = nt * 16 + lr;
    atomicAdd(&ls[col], s0[nt]);
    atomicAdd(&ls[col + 256], s1[nt]);
  }
  __syncthreads();
  if (tid < 256) {
    atomicAdd(&bnsum[tid], ls[tid]);
    atomicAdd(&bnsum[HD2 + tid], ls[tid + 256]);
  }
}

__global__ void k_bnfin(const float* bnsum, const float* gamma, const float* beta, float* a12) {
  int c = threadIdx.x;
  if (c < HD2) {
    float mu = bnsum[c] * (1.f / (float)NN);
    float var = fmaxf(bnsum[HD2 + c] * (1.f / (float)NN) - mu * mu, 0.f);
    float rs = rsqrtf(var + BNEPS);
    float g = gamma[c] * rs;
    a12[c] = g;
    a12[HD2 + c] = beta[c] - mu * g;
  }
}

// ---------------- GEMM2 (MFMA): H = relu( relu(BN(Z)) @ W2 + b2 ) ----------------
__launch_bounds__(256, 2)
__global__ void k_gemm2(const ushort_t* __restrict__ Zin, const ushort_t* __restrict__ Bt,
                        const float* __restrict__ bias, const float* __restrict__ a12,
                        ushort_t* __restrict__ Hout) {
  __shared__ ushort_t Bs[128 * 256];  // 64KB swizzled, row len 512B
  __shared__ ushort_t As[64 * 128];   // 16KB swizzled (one K-half)
  const int tid = threadIdx.x;
#pragma unroll
  for (int i = 0; i < 16; ++i) {
    int chunk = tid + 256 * i;
    int n = chunk >> 5, c = chunk & 31;
    bf16x8 v = *(const bf16x8*)&Bt[n * 256 + c * 8];
    *(bf16x8*)((char*)Bs + n * 512 + ((c * 16) ^ ((n & 7) << 4))) = v;
  }
  const int wv = tid >> 6, ln = tid & 63;
  const int lr = ln & 15, lg = ln >> 4;
  float a1v[2][8], a2v[2][8];
#pragma unroll
  for (int h = 0; h < 2; ++h)
#pragma unroll
    for (int j = 0; j < 8; ++j) {
      int k = h * 128 + (tid & 15) * 8 + j;
      a1v[h][j] = a12[k];
      a2v[h][j] = a12[HD2 + k];
    }
  float bb[8];
#pragma unroll
  for (int nt = 0; nt < 8; ++nt) bb[nt] = bias[nt * 16 + lr];

  for (int t = blockIdx.x; t < G1TILES; t += GEMM_GRID) {
    int row0 = t * 64;
    f32x4 acc[8];
#pragma unroll
    for (int nt = 0; nt < 8; ++nt) acc[nt] = (f32x4){0.f, 0.f, 0.f, 0.f};
#pragma unroll
    for (int h = 0; h < 2; ++h) {
#pragma unroll
      for (int i = 0; i < 4; ++i) {
        int chunk = tid + 256 * i;
        int r = chunk >> 4, c = chunk & 15;
        int grow = row0 + r; if (grow >= NN) grow = NN - 1;
        bf16x8 v = *(const bf16x8*)&Zin[(size_t)grow * HD2 + h * 128 + c * 8];
        bf16x8 o;
#pragma unroll
        for (int j = 0; j < 8; ++j) {
          float f = bfl((unsigned short)v[j]) * a1v[h][j] + a2v[h][j];
          o[j] = (short)fbf(fmaxf(f, 0.f));
        }
        *(bf16x8*)((char*)As + r * 256 + ((c * 16) ^ ((r & 7) << 4))) = o;
      }
      __syncthreads();
      int arow = wv * 16 + lr;
      bf16x8 af[4];
#pragma unroll
      for (int ks = 0; ks < 4; ++ks)
        af[ks] = *(bf16x8*)((char*)As + arow * 256 + ((ks * 64 + lg * 16) ^ ((arow & 7) << 4)));
#pragma unroll
      for (int nt = 0; nt < 8; ++nt) {
        int bn = nt * 16 + lr;
#pragma unroll
        for (int ks = 0; ks < 4; ++ks) {
          bf16x8 bfr = *(bf16x8*)((char*)Bs + bn * 512 +
                                  (((h * 16 + ks * 4 + lg) * 16) ^ ((bn & 7) << 4)));
          acc[nt] = __builtin_amdgcn_mfma_f32_16x16x32_bf16(af[ks], bfr, acc[nt], 0, 0, 0);
        }
      }
      __syncthreads();
    }
#pragma unroll
    for (int nt = 0; nt < 8; ++nt) {
      int col = nt * 16 + lr;
#pragma unroll
      for (int j = 0; j < 4; ++j) {
        int grow = row0 + wv * 16 + lg * 4 + j;
        if (grow < NN) Hout[(size_t)grow * FD + col] = fbf(fmaxf(acc[nt][j] + bb[nt], 0.f));
      }
    }
  }
}

// ---------------- fused pool + FC + log_softmax (one block per graph) ----------------
__launch_bounds__(256)
__global__ void k_pool_fc(const ushort_t* __restrict__ hb, const int* __restrict__ gstart,
                          const int* __restrict__ gcnti, const float* __restrict__ fcW,
                          const float* __restrict__ fcb, float* __restrict__ out) {
  __shared__ float pool4[4][512];
  __shared__ float wred[4][NCLS];
  int g = blockIdx.x, t = threadIdx.x;
  int start = gstart[g], cnt = gcnti[g];
  int chunk = t & 63, ro = t >> 6;
  int L = chunk >> 4, cc = (chunk & 15) * 8;
  const ushort_t* hL = hb + (size_t)L * NN * FD;
  float s[8] = {};
  for (int r = start + ro; r < start + cnt; r += 4) {
    bf16x8 v = *(const bf16x8*)&hL[(size_t)r * FD + cc];
#pragma unroll
    for (int j = 0; j < 8; ++j) s[j] += bfl((unsigned short)v[j]);
  }
#pragma unroll
  for (int j = 0; j < 8; ++j) pool4[ro][chunk * 8 + j] = s[j];
  __syncthreads();
  float inv = 1.f / fmaxf((float)cnt, 1.f);
  float pA = (pool4[0][t] + pool4[1][t] + pool4[2][t] + pool4[3][t]) * inv;
  float pB = (pool4[0][t + 256] + pool4[1][t + 256] + pool4[2][t + 256] + pool4[3][t + 256]) * inv;
  float pacc[NCLS];
#pragma unroll
  for (int c = 0; c < NCLS; ++c)
    pacc[c] = pA * fcW[t * NCLS + c] + pB * fcW[(t + 256) * NCLS + c];
#pragma unroll
  for (int off = 32; off > 0; off >>= 1)
#pragma unroll
    for (int c = 0; c < NCLS; ++c) pacc[c] += __shfl_down(pacc[c], off);
  if ((t & 63) == 0)
#pragma unroll
    for (int c = 0; c < NCLS; ++c) wred[t >> 6][c] = pacc[c];
  __syncthreads();
  if (t == 0) {
    float lg[NCLS];
    float mx = -1e30f;
#pragma unroll
    for (int c = 0; c < NCLS; ++c) {
      lg[c] = wred[0][c] + wred[1][c] + wred[2][c] + wred[3][c] + fcb[c];
      mx = fmaxf(mx, lg[c]);
    }
    float se = 0.f;
#pragma unroll
    for (int c = 0; c < NCLS; ++c) se += expf(lg[c] - mx);
    float lse = mx + logf(se);
#pragma unroll
    for (int c = 0; c < NCLS; ++c) out[(size_t)g * NCLS + c] = lg[c] - lse;
  }
}

// ---------------- host ----------------
extern "C" void kernel_launch(void* const* d_in, const int* in_sizes, int n_in,
                              void* d_out, int out_size, void* d_ws, size_t ws_size,
                              hipStream_t stream) {
  const float* x      = (const float*)d_in[0];
  const int*   ei     = (const int*)d_in[1];
  const int*   batch  = (const int*)d_in[3];
  const float* W1     = (const float*)d_in[4];
  const float* b1     = (const float*)d_in[5];
  const float* gamma1 = (const float*)d_in[6];
  const float* beta1  = (const float*)d_in[7];
  const float* W2     = (const float*)d_in[8];
  const float* b2     = (const float*)d_in[9];
  const float* fcW    = (const float*)d_in[10];
  const float* fcb    = (const float*)d_in[11];
  float* out = (float*)d_out;

  char* p = (char*)d_ws;
  auto alloc = [&](size_t bytes) {
    char* r = p;
    p += (bytes + 255) & ~(size_t)255;
    return r;
  };
  ushort_t* xbf   = (ushort_t*)alloc((size_t)NN * FD * 2);
  ushort_t* tbuf  = (ushort_t*)alloc((size_t)NN * FD * 2);
  ushort_t* Zbuf  = (ushort_t*)alloc((size_t)NN * HD2 * 2);
  ushort_t* hb    = (ushort_t*)alloc((size_t)NLAYERS * NN * FD * 2);
  ushort_t* W1t   = (ushort_t*)alloc((size_t)NLAYERS * FD * HD2 * 2);
  ushort_t* W2t   = (ushort_t*)alloc((size_t)NLAYERS * FD * HD2 * 2);
  float* inv_deg  = (float*)alloc((size_t)NN * 4);
  float* bnsum    = (float*)alloc(2 * HD2 * 4);
  float* a12      = (float*)alloc(2 * HD2 * 4);
  int* degi       = (int*)alloc((size_t)NN * 4);
  int* rowptr     = (int*)alloc((size_t)(NN + 1) * 4);
  int* cursor     = (int*)alloc((size_t)NN * 4);
  int* csr        = (int*)alloc((size_t)NE * 4);
  int* bsum       = (int*)alloc(512 * 4);
  int* src32      = (int*)alloc((size_t)NE * 4);
  int* dst32      = (int*)alloc((size_t)NE * 4);
  int* batch32    = (int*)alloc((size_t)NN * 4);
  int* gcnti      = (int*)alloc((size_t)NGR * 4);
  int* gstart     = (int*)alloc((size_t)NGR * 4);
  int* flag       = (int*)alloc(256);

  const int EB = (NE + 255) / 256;
  const int NB = (NN + 255) / 256;

  k_detect<<<1, 256, 0, stream>>>(ei, flag);
  k_repack<<<EB, 256, 0, stream>>>(ei, batch, flag, src32, dst32, batch32);
  k_init<<<NB, 256, 0, stream>>>(degi);
  k_deg<<<EB, 256, 0, stream>>>(dst32, degi);
  k_gstats<<<1, 512, 0, stream>>>(batch32, gstart, gcnti);
  k_scan1<<<NB, 256, 0, stream>>>(degi, rowptr, bsum);
  k_scan2<<<1, 512, 0, stream>>>(bsum, NB);
  k_scan3_cursor<<<NB, 256, 0, stream>>>(rowptr, bsum, cursor, degi, inv_deg);
  k_scatter<<<EB, 256, 0, stream>>>(src32, dst32, cursor, csr);
  k_cvt_x<<<(NN * FD / 8 + 255) / 256, 256, 0, stream>>>(x, xbf);
  k_cvt_w<<<(NLAYERS * FD * HD2 + 255) / 256, 256, 0, stream>>>(W1, W2, W1t, W2t);

  const ushort_t* hin = xbf;
  for (int L = 0; L < NLAYERS; ++L) {
    k_agg<<<NN / 4, 256, 0, stream>>>(hin, rowptr, csr, inv_deg, tbuf, bnsum);
    k_gemm1<<<GEMM_GRID, 256, 0, stream>>>(tbuf, W1t + (size_t)L * FD * HD2,
                                           b1 + (size_t)L * HD2, Zbuf, bnsum);
    k_bnfin<<<1, 256, 0, stream>>>(bnsum, gamma1 + (size_t)L * HD2, beta1 + (size_t)L * HD2, a12);
    k_gemm2<<<GEMM_GRID, 256, 0, stream>>>(Zbuf, W2t + (size_t)L * FD * HD2,
                                           b2 + (size_t)L * FD, a12,
                                           hb + (size_t)L * NN * FD);
    hin = hb + (size_t)L * NN * FD;
  }
  k_pool_fc<<<NGR, 256, 0, stream>>>(hb, gstart, gcnti, fcW, fcb, out);
}